// Round 17
// baseline (1488.727 us; speedup 1.0000x reference)
//
#include <hip/hip_runtime.h>

#define K_ACTIVE 32
#define MULTI_K 64
#define AUX_K 64
#define DEAD_THRESH 256
#define BUF_CAP 2097152u
#define STG_CAP 4096
#define SORT_CAP 4096
#define MKCAND_CAP 1024

typedef unsigned int u32;
typedef unsigned long long u64;
typedef unsigned short ushort_t;
typedef __bf16 bf16x8 __attribute__((ext_vector_type(8)));
typedef float f32x4 __attribute__((ext_vector_type(4)));

__device__ __forceinline__ u32 fmap_signed_bits(u32 u) {
  return (u & 0x80000000u) ? ~u : (u | 0x80000000u);
}

__device__ __forceinline__ u32 bf16_rne(float f) {
  u32 u = __float_as_uint(f);
  return (u + 0x7FFFu + ((u >> 16) & 1u)) >> 16;
}

__device__ __forceinline__ void gload16(const void* g, void* s) {
  __builtin_amdgcn_global_load_lds(
      (const __attribute__((address_space(1))) void*)g,
      (__attribute__((address_space(3))) void*)s, 16, 0, 0);
}

// ---------------- transpose dec_w [D,M] -> dec_wT [M,D] ----------------
__global__ void transpose_k(const float* __restrict__ in, float* __restrict__ out, int D, int M) {
  __shared__ float tile[32][33];
  const int bx = blockIdx.x * 32;
  const int by = blockIdx.y * 32;
  const int tx = threadIdx.x, ty = threadIdx.y;
  #pragma unroll
  for (int i = 0; i < 32; i += 8)
    tile[ty + i][tx] = in[(size_t)(by + ty + i) * M + bx + tx];
  __syncthreads();
  #pragma unroll
  for (int i = 0; i < 32; i += 8)
    out[(size_t)(bx + ty + i) * D + by + tx] = tile[tx][ty + i];
}

// ---------------- split conversions ----------------
__global__ void convA_k(const float* __restrict__ X, const float* __restrict__ IB,
                        ushort_t* __restrict__ AH, ushort_t* __restrict__ AL, int D) {
  const int idx = blockIdx.x * 256 + threadIdx.x;
  const int row = idx >> 7;
  const int dpos = (idx & 127) << 3;
  const float4* xr = reinterpret_cast<const float4*>(X + (size_t)row * D + dpos);
  const float4* br = reinterpret_cast<const float4*>(IB + dpos);
  float4 x0 = xr[0], x1 = xr[1], b0 = br[0], b1 = br[1];
  float c[8] = {x0.x - b0.x, x0.y - b0.y, x0.z - b0.z, x0.w - b0.w,
                x1.x - b1.x, x1.y - b1.y, x1.z - b1.z, x1.w - b1.w};
  u32 hw[4], lw[4];
  #pragma unroll
  for (int j = 0; j < 4; ++j) {
    u32 h0 = bf16_rne(c[2 * j]), h1 = bf16_rne(c[2 * j + 1]);
    float r0 = c[2 * j] - __uint_as_float(h0 << 16);
    float r1 = c[2 * j + 1] - __uint_as_float(h1 << 16);
    hw[j] = h0 | (h1 << 16);
    lw[j] = bf16_rne(r0) | (bf16_rne(r1) << 16);
  }
  reinterpret_cast<uint4*>(AH)[idx] = make_uint4(hw[0], hw[1], hw[2], hw[3]);
  reinterpret_cast<uint4*>(AL)[idx] = make_uint4(lw[0], lw[1], lw[2], lw[3]);
}

__global__ void convW_k(const float* __restrict__ W,
                        ushort_t* __restrict__ WH, ushort_t* __restrict__ WL) {
  const int idx = blockIdx.x * 256 + threadIdx.x;
  const float4* wr = reinterpret_cast<const float4*>(W) + (size_t)idx * 2;
  float4 x0 = wr[0], x1 = wr[1];
  float c[8] = {x0.x, x0.y, x0.z, x0.w, x1.x, x1.y, x1.z, x1.w};
  u32 hw[4], lw[4];
  #pragma unroll
  for (int j = 0; j < 4; ++j) {
    u32 h0 = bf16_rne(c[2 * j]), h1 = bf16_rne(c[2 * j + 1]);
    float r0 = c[2 * j] - __uint_as_float(h0 << 16);
    float r1 = c[2 * j + 1] - __uint_as_float(h1 << 16);
    hw[j] = h0 | (h1 << 16);
    lw[j] = bf16_rne(r0) | (bf16_rne(r1) << 16);
  }
  reinterpret_cast<uint4*>(WH)[idx] = make_uint4(hw[0], hw[1], hw[2], hw[3]);
  reinterpret_cast<uint4*>(WL)[idx] = make_uint4(lw[0], lw[1], lw[2], lw[3]);
}

// ---------------- MFMA GEMM (+ fused hist1 + col-max in epilogue) ----------------
__global__ __launch_bounds__(256) void gemm_mfma(
    const ushort_t* __restrict__ AH, const ushort_t* __restrict__ AL,
    const ushort_t* __restrict__ WH, const ushort_t* __restrict__ WL,
    const float* __restrict__ NB, float* __restrict__ OUT,
    u32* __restrict__ GH, u32* __restrict__ CM, int M) {
  extern __shared__ char smem[];                 // 32768 B
  ushort_t* sA = (ushort_t*)smem;
  ushort_t* sB = (ushort_t*)(smem + 16384);
  const int tid = threadIdx.x;
  const int wave = tid >> 6, lane = tid & 63;
  const int bm = blockIdx.y * 128, bn = blockIdx.x * 128;
  const int wm = wave & 1, wn = wave >> 1;

  f32x4 acc[4][4];
  #pragma unroll
  for (int i = 0; i < 4; ++i)
    #pragma unroll
    for (int j = 0; j < 4; ++j) acc[i][j] = (f32x4){0.f, 0.f, 0.f, 0.f};

  int rowA[4], cbS[4];
  #pragma unroll
  for (int r = 0; r < 4; ++r) {
    int o = ((wave << 2) + r) * 1024 + lane * 16;
    int row = o >> 7;
    int cb = o & 127;
    rowA[r] = row;
    cbS[r] = cb ^ ((row & 7) << 4);   // pre-swizzled source column byte (rule #21)
  }
  const int cl = lane & 15, kg = lane >> 4;

  for (int kt = 0; kt < 48; ++kt) {
    const int ph = kt >> 4;
    const size_t kb = (size_t)((kt & 15) << 6) * 2;
    const ushort_t* Asrc = (ph == 1) ? AL : AH;
    const ushort_t* Bsrc = (ph == 2) ? WL : WH;
    #pragma unroll
    for (int r = 0; r < 4; ++r) {
      gload16((const char*)Asrc + ((size_t)(bm + rowA[r]) * 2048 + kb + cbS[r]),
              (char*)sA + (((wave << 2) + r) << 10));
      gload16((const char*)Bsrc + ((size_t)(bn + rowA[r]) * 2048 + kb + cbS[r]),
              (char*)sB + (((wave << 2) + r) << 10));
    }
    __syncthreads();
    #pragma unroll
    for (int ks = 0; ks < 2; ++ks) {
      const int kbyte = ks * 64 + kg * 16;
      bf16x8 af[4], bfr[4];
      #pragma unroll
      for (int mi = 0; mi < 4; ++mi) {
        const int rA = wm * 64 + mi * 16 + cl;
        af[mi] = *reinterpret_cast<const bf16x8*>(
            (const char*)sA + rA * 128 + (kbyte ^ ((rA & 7) << 4)));
      }
      #pragma unroll
      for (int ni = 0; ni < 4; ++ni) {
        const int rB = wn * 64 + ni * 16 + cl;
        bfr[ni] = *reinterpret_cast<const bf16x8*>(
            (const char*)sB + rB * 128 + (kbyte ^ ((rB & 7) << 4)));
      }
      #pragma unroll
      for (int mi = 0; mi < 4; ++mi)
        #pragma unroll
        for (int ni = 0; ni < 4; ++ni)
          acc[mi][ni] = __builtin_amdgcn_mfma_f32_16x16x32_bf16(af[mi], bfr[ni], acc[mi][ni], 0, 0, 0);
    }
    __syncthreads();
  }

  // epilogue: 4-replica 2048-bin histogram (hist1, zero-skipped) + col-max (CM)
  u32* eh = (u32*)smem;
  for (int i = tid; i < 8192; i += 256) eh[i] = 0;
  __syncthreads();
  const int rg = lane >> 4;
  const int rb = (lane & 3) * 2048;
  u32 zcnt = 0;
  #pragma unroll
  for (int ni = 0; ni < 4; ++ni) {
    const int col = bn + wn * 64 + ni * 16 + cl;
    const float nbv = NB[col];
    float mx = 0.f;
    #pragma unroll
    for (int mi = 0; mi < 4; ++mi) {
      const int row0 = bm + wm * 64 + mi * 16 + rg * 4;
      #pragma unroll
      for (int r = 0; r < 4; ++r) {
        const float val = acc[mi][ni][r] + nbv;
        OUT[(size_t)(row0 + r) * M + col] = val;
        const float a = (val > 0.f) ? val : 0.f;
        mx = fmaxf(mx, a);
        const u32 bin = __float_as_uint(a) >> 21;
        if (bin) atomicAdd(&eh[rb + bin], 1u); else ++zcnt;  // zero-skip (~50%)
      }
    }
    mx = fmaxf(mx, __shfl_xor(mx, 16));
    mx = fmaxf(mx, __shfl_xor(mx, 32));
    if (rg == 0) atomicMax(&CM[col], __float_as_uint(mx));
  }
  #pragma unroll
  for (int o = 32; o > 0; o >>= 1) zcnt += __shfl_down(zcnt, o);
  if (lane == 0 && zcnt) atomicAdd(&eh[0], zcnt);
  __syncthreads();
  for (int i = tid; i < 2048; i += 256) {
    u32 s = eh[i] + eh[2048 + i] + eh[4096 + i] + eh[6144 + i];
    if (s) atomicAdd(&GH[i], s);
  }
}

// parallel suffix-scan cutoff finder; phase 1: bits[31:21]; phase 2: bits[20:10]
__global__ void scan_k(const u32* __restrict__ H, u32* __restrict__ PRM, u32 K, int phase) {
  __shared__ u32 suf[256];
  const int t = threadIdx.x;
  u32 h[8], ls[8];
  #pragma unroll
  for (int j = 0; j < 8; ++j) h[j] = H[t * 8 + j];
  u32 run = 0;
  #pragma unroll
  for (int j = 7; j >= 0; --j) { run += h[j]; ls[j] = run; }
  suf[t] = run;
  __syncthreads();
  for (int off = 1; off < 256; off <<= 1) {
    u32 v = (t + off < 256) ? suf[t + off] : 0u;
    __syncthreads();
    suf[t] += v;
    __syncthreads();
  }
  const u32 rightOf = (t < 255) ? suf[t + 1] : 0u;
  const u32 base = (phase == 2) ? PRM[1] : 0u;
  #pragma unroll
  for (int j = 0; j < 8; ++j) {
    u32 Sb = base + rightOf + ls[j];
    u32 Sb1 = base + rightOf + ((j < 7) ? ls[j + 1] : 0u);
    if (Sb >= K && Sb1 < K) {
      int b = t * 8 + j;
      if (phase == 1) { PRM[0] = (u32)b; PRM[1] = Sb1; }
      else { PRM[2] = (PRM[0] << 11) | (u32)b; PRM[3] = K - Sb1; }
    }
  }
}

// hist2: refine bin1 by next 11 bits; stage bin1 candidates per-block in LDS
__global__ void hist2_k(const float4* __restrict__ P4, size_t N4, u32* __restrict__ PRM,
                        u32* __restrict__ GH, float* __restrict__ BV, u32* __restrict__ BI) {
  __shared__ float sv[STG_CAP];
  __shared__ u32 si[STG_CAP];
  __shared__ u32 scnt, sbase;
  const int tid = threadIdx.x;
  if (tid == 0) scnt = 0;
  __syncthreads();
  const u32 b1 = PRM[0];
  const size_t step = (size_t)gridDim.x * blockDim.x;
  for (size_t i = (size_t)blockIdx.x * blockDim.x + tid; i < N4; i += step) {
    float4 vv = P4[i];
    float va[4] = {vv.x, vv.y, vv.z, vv.w};
    #pragma unroll
    for (int c = 0; c < 4; ++c) {
      float a = (va[c] > 0.f) ? va[c] : 0.f;
      u32 u = __float_as_uint(a);
      if ((u >> 21) == b1) {
        atomicAdd(&GH[(u >> 10) & 2047u], 1u);
        u32 p = atomicAdd(&scnt, 1u);
        if (p < STG_CAP) { sv[p] = a; si[p] = (u32)(i * 4 + c); }
        else {
          u32 g = atomicAdd(&PRM[8], 1u);
          if (g < BUF_CAP) { BV[g] = a; BI[g] = (u32)(i * 4 + c); }
        }
      }
    }
  }
  __syncthreads();
  u32 n = scnt < STG_CAP ? scnt : STG_CAP;
  if (tid == 0) sbase = atomicAdd(&PRM[8], n);
  __syncthreads();
  const u32 base = sbase;
  for (u32 i = tid; i < n; i += 256) {
    u32 g = base + i;
    if (g < BUF_CAP) { BV[g] = sv[i]; BI[g] = si[i]; }
  }
}

// collect2: filter stored bin1 candidates down to the 22-bit cutoff bin (tiny pass)
__global__ void collect2_k(u32* __restrict__ PRM, const float* __restrict__ BV,
                           const u32* __restrict__ BI, float* __restrict__ BV2,
                           u32* __restrict__ BI2) {
  const u32 pc = PRM[2];
  u32 nb1 = PRM[8]; if (nb1 > BUF_CAP) nb1 = BUF_CAP;
  const u32 step = gridDim.x * blockDim.x;
  for (u32 i = blockIdx.x * blockDim.x + threadIdx.x; i < nb1; i += step) {
    float a = BV[i];
    if ((__float_as_uint(a) >> 10) == pc) {
      u32 pos = atomicAdd(&PRM[9], 1u);
      if (pos < SORT_CAP) { BV2[pos] = a; BI2[pos] = BI[i]; }
    }
  }
}

__global__ void sortmark_k(u32* __restrict__ PRM, const float* __restrict__ BV, const u32* __restrict__ BI,
                           float* __restrict__ SV, u32* __restrict__ SI, u32* __restrict__ CF, int M) {
  __shared__ u64 keys[SORT_CAP];
  const int tid = threadIdx.x;
  u32 nb = PRM[9]; if (nb > SORT_CAP) nb = SORT_CAP;
  const u32 krem = PRM[3];
  if (nb == 0) { if (tid == 0) PRM[5] = 0; return; }
  u32 np = 1; while (np < nb) np <<= 1;
  for (u32 i = tid; i < np; i += 256)
    keys[i] = (i < nb) ? ((((u64)__float_as_uint(BV[i])) << 32) | (u64)(0xFFFFFFFFu - BI[i])) : 0ull;
  __syncthreads();
  for (u32 k = 2; k <= np; k <<= 1) {
    for (u32 j = k >> 1; j > 0; j >>= 1) {
      for (u32 i = tid; i < np; i += 256) {
        u32 ixj = i ^ j;
        if (ixj > i) {
          u64 a = keys[i], b = keys[ixj];
          bool up = ((i & k) == 0);
          if (up ? (a < b) : (a > b)) { keys[i] = b; keys[ixj] = a; }
        }
      }
      __syncthreads();
    }
  }
  u32 nsel = krem < nb ? krem : nb;
  for (u32 t = tid; t < nsel; t += 256) {
    u64 kk = keys[t];
    u32 flat = 0xFFFFFFFFu - (u32)(kk & 0xFFFFFFFFull);
    float val = __uint_as_float((u32)(kk >> 32));
    SI[t] = flat; SV[t] = val;
    if (val > 0.f) CF[flat % (u32)M] = 1u;
  }
  if (tid == 0) PRM[5] = nsel;
}

// ---------------- dead mask: active = boundary-mark OR col-max above cutoff bin ----------------
__global__ void dead_k(const u32* __restrict__ CF, const u32* __restrict__ CM,
                       const int* __restrict__ ST, const u32* __restrict__ PRM,
                       u32* __restrict__ DW, int M) {
  int w = blockIdx.x * blockDim.x + threadIdx.x;
  if (w >= M / 32) return;
  const u32 pc = PRM[2];
  u32 bits = 0;
  for (int i = 0; i < 32; ++i) {
    int n = w * 32 + i;
    bool active = (CF[n] != 0) || ((CM[n] >> 10) > pc);
    if (!active && (ST[n] + 1) > DEAD_THRESH) bits |= (1u << i);
  }
  DW[w] = bits;
}

// ---------------- per-row top-64 select (value desc, index asc) ----------------
// keys[] (threshold fast path of rowk_multik) aliases hist[] — mutually
// exclusive lifetimes, no extra LDS (r14 lesson).
struct TopkSh {
  union {
    u32 hist[16 * 257];
    u64 keys[MKCAND_CAP];
  } u;
  u32 wred[4];
  u32 prefix, need, scnt;
  int selN[64];
  float selV[64];
};

template<bool ZSKIP>
__device__ __forceinline__ void row_topk64(const float (&v)[64], int tid, TopkSh* S) {
  const int lane = tid & 63, wid = tid >> 6;
  u32 zp = 0, zn = 0;
  if (ZSKIP) {
    #pragma unroll
    for (int j = 0; j < 64; ++j) {
      u32 ub = __float_as_uint(v[j]);
      zp += (ub == 0u);
      zn += (ub == 0x80000000u);
    }
    #pragma unroll
    for (int o = 32; o > 0; o >>= 1) { zp += __shfl_down(zp, o); zn += __shfl_down(zn, o); }
  }
  u32 pref = 0, need = 64;
  for (int p = 0; p < 4; ++p) {
    const int sh = 24 - 8 * p;
    for (int i = tid; i < 16 * 257; i += 256) S->u.hist[i] = 0;
    if (p == 0 && tid == 0) S->scnt = 0;
    __syncthreads();
    const int rb = (tid & 15) * 257;
    #pragma unroll
    for (int j = 0; j < 64; ++j) {
      u32 ub = __float_as_uint(v[j]);
      if (ZSKIP && ((ub << 1) == 0u)) continue;
      u32 mu = fmap_signed_bits(ub);
      if (p == 0 || (mu >> (sh + 8)) == pref)
        atomicAdd(&S->u.hist[rb + ((mu >> sh) & 255u)], 1u);
    }
    if (ZSKIP && lane == 0) {
      const u32 mup = 0x80000000u, mun = 0x7FFFFFFFu;
      if (zp && (p == 0 || (mup >> (sh + 8)) == pref))
        atomicAdd(&S->u.hist[wid * 257 + ((mup >> sh) & 255u)], zp);
      if (zn && (p == 0 || (mun >> (sh + 8)) == pref))
        atomicAdd(&S->u.hist[wid * 257 + ((mun >> sh) & 255u)], zn);
    }
    __syncthreads();
    u32 own = 0;
    #pragma unroll
    for (int r = 0; r < 16; ++r) own += S->u.hist[r * 257 + tid];
    u32 x = own;
    #pragma unroll
    for (int o = 1; o < 64; o <<= 1) {
      u32 y = __shfl_down(x, o);
      x += (lane + o < 64) ? y : 0u;
    }
    if (lane == 0) S->wred[wid] = x;
    __syncthreads();
    u32 Sb = x;
    for (int w = wid + 1; w < 4; ++w) Sb += S->wred[w];
    u32 below = Sb - own;
    if (Sb >= need && below < need) {
      S->prefix = (pref << 8) | (u32)tid;
      S->need = need - below;
    }
    __syncthreads();
    pref = S->prefix; need = S->need;
  }
  const u32 muc = pref, neq = need;
  u32 myeq = 0;
  #pragma unroll
  for (int j = 0; j < 64; ++j) {
    u32 mu = fmap_signed_bits(__float_as_uint(v[j]));
    if (mu > muc) {
      u32 pos = atomicAdd(&S->scnt, 1u);
      S->selN[pos] = tid * 64 + j;
      S->selV[pos] = v[j];
    } else if (mu == muc) ++myeq;
  }
  u32 xs = myeq;
  #pragma unroll
  for (int o = 1; o < 64; o <<= 1) {
    u32 y = __shfl_up(xs, o);
    xs += (lane >= o) ? y : 0u;
  }
  if (lane == 63) S->wred[wid] = xs;
  __syncthreads();
  u32 base = 0;
  for (int w = 0; w < wid; ++w) base += S->wred[w];
  u32 g = base + xs - myeq;
  const u32 a0 = S->scnt;
  #pragma unroll
  for (int j = 0; j < 64; ++j) {
    u32 mu = fmap_signed_bits(__float_as_uint(v[j]));
    if (mu == muc) {
      if (g < neq) { S->selN[a0 + g] = tid * 64 + j; S->selV[a0 + g] = v[j]; }
      ++g;
    }
  }
  __syncthreads();
}

__device__ __forceinline__ void load_row64(const float* rowp, float (&v)[64]) {
  #pragma unroll
  for (int j = 0; j < 16; ++j) {
    float4 t = reinterpret_cast<const float4*>(rowp)[j];
    v[4 * j + 0] = t.x; v[4 * j + 1] = t.y; v[4 * j + 2] = t.z; v[4 * j + 3] = t.w;
  }
}

// ---------------- multik top-64 + decode ----------------
// Fast path: per-row top-64 cutoff ~2.66 sigma >> 2.0, so collect candidates
// > 2.0 (~260-420 of 16384), bitonic-sort by (value desc, index asc) — the
// same total order as the radix path — and take the first 64. The selected
// SET is bit-identical; MR consumes only the set. Guarded: count outside
// [64, MKCAND_CAP] falls back to the exact radix select.
__launch_bounds__(256, 2)
__global__ void rowk_multik(const float* __restrict__ PRE, const float* __restrict__ WT,
                            const float* __restrict__ IB, float* __restrict__ MR,
                            int M, int D) {
  __shared__ TopkSh S;
  const int b = blockIdx.x, tid = threadIdx.x;
  float v[64];
  load_row64(PRE + (size_t)b * M + tid * 64, v);

  if (tid == 0) S.scnt = 0;
  __syncthreads();
  #pragma unroll
  for (int j = 0; j < 64; ++j) {
    if (v[j] > 2.0f) {
      u32 p = atomicAdd(&S.scnt, 1u);
      if (p < MKCAND_CAP)
        S.u.keys[p] = (((u64)(__float_as_uint(v[j]) | 0x80000000u)) << 32)
                    | (u64)(0xFFFFFFFFu - (u32)(tid * 64 + j));
    }
  }
  __syncthreads();
  const u32 n = S.scnt;
  if (n >= 64u && n <= (u32)MKCAND_CAP) {
    u32 np = 1; while (np < n) np <<= 1;
    for (u32 i = tid; i < np; i += 256) if (i >= n) S.u.keys[i] = 0ull;
    __syncthreads();
    for (u32 k = 2; k <= np; k <<= 1) {
      for (u32 j = k >> 1; j > 0; j >>= 1) {
        for (u32 i = tid; i < np; i += 256) {
          u32 ixj = i ^ j;
          if (ixj > i) {
            u64 a = S.u.keys[i], b2 = S.u.keys[ixj];
            bool up = ((i & k) == 0);
            if (up ? (a < b2) : (a > b2)) { S.u.keys[i] = b2; S.u.keys[ixj] = a; }
          }
        }
        __syncthreads();
      }
    }
    if (tid < 64) {
      u64 kk = S.u.keys[tid];
      S.selV[tid] = __uint_as_float((u32)(kk >> 32) & 0x7FFFFFFFu);
      S.selN[tid] = (int)(0xFFFFFFFFu - (u32)kk);
    }
    __syncthreads();
  } else {
    row_topk64<false>(v, tid, &S);   // exact fallback (never hit statistically)
  }

  const int d0 = tid * 4;
  float4 acc = *reinterpret_cast<const float4*>(IB + d0);
  for (int i = 0; i < 64; ++i) {
    float w = S.selV[i];
    if (w > 0.f) {
      const float4 wv = *reinterpret_cast<const float4*>(WT + (size_t)S.selN[i] * D + d0);
      acc.x = fmaf(w, wv.x, acc.x); acc.y = fmaf(w, wv.y, acc.y);
      acc.z = fmaf(w, wv.z, acc.z); acc.w = fmaf(w, wv.w, acc.w);
    }
  }
  *reinterpret_cast<float4*>(MR + (size_t)b * D + d0) = acc;
}

// ---------------- aux top-64 over dead_pre with exact tie semantics ----------------
__launch_bounds__(256, 2)
__global__ void rowk_aux(const float* __restrict__ PRE, const u32* __restrict__ DW,
                         float* __restrict__ AV, float* __restrict__ AI, int M) {
  __shared__ TopkSh S;
  __shared__ u64 skey[64];
  __shared__ int sN2[64];
  __shared__ float sV2[64];
  const int b = blockIdx.x, tid = threadIdx.x;
  float v[64];
  load_row64(PRE + (size_t)b * M + tid * 64, v);
  const u32 mw0 = DW[tid * 2], mw1 = DW[tid * 2 + 1];
  #pragma unroll
  for (int j = 0; j < 64; ++j) {
    u32 bit = ((j < 32 ? mw0 : mw1) >> (j & 31)) & 1u;
    v[j] = bit ? v[j] : (v[j] * 0.0f);   // preserves signed zero like the reference
  }
  row_topk64<true>(v, tid, &S);
  if (tid < 64) {
    float vv = S.selV[tid];
    int col = S.selN[tid];
    u32 mu = fmap_signed_bits(__float_as_uint(vv));
    skey[tid] = (((u64)mu) << 32) | (u64)(0xFFFFFFFFu - (u32)col);
  }
  __syncthreads();
  if (tid < 64) {
    u64 mine = skey[tid];
    int rank = 0;
    for (int j = 0; j < 64; ++j) rank += (skey[j] > mine) ? 1 : 0;
    sN2[rank] = S.selN[tid]; sV2[rank] = S.selV[tid];
  }
  __syncthreads();
  if (tid < 64) {
    AV[(size_t)b * AUX_K + tid] = sV2[tid] > 0.f ? sV2[tid] : 0.f;
    AI[(size_t)b * AUX_K + tid] = (float)sN2[tid];
  }
}

// ---------------- activ scatter (in place) + sparse recon decode ----------------
__launch_bounds__(256, 2)
__global__ void rowk_scatter(float* __restrict__ ACT, const float* __restrict__ WT,
                             const float* __restrict__ IB, float* __restrict__ RC,
                             const u32* __restrict__ PRM, const float* __restrict__ SV,
                             const u32* __restrict__ SI, int M, int D) {
  __shared__ int lsN[2048]; __shared__ float lsV[2048];
  __shared__ int ovN[256]; __shared__ float ovV[256];
  __shared__ u32 ovc, lc;
  const int b = blockIdx.x, tid = threadIdx.x;
  float* rowp = ACT + (size_t)b * M + tid * 64;
  float v[64];
  load_row64(rowp, v);
  const u32 pc = PRM[2];
  #pragma unroll
  for (int j = 0; j < 64; ++j) {
    float a = (v[j] > 0.f) ? v[j] : 0.f;
    v[j] = ((__float_as_uint(a) >> 10) > pc) ? a : 0.f;
  }
  if (tid == 0) ovc = 0;
  __syncthreads();
  const u32 nbs = PRM[5];
  for (u32 t = tid; t < nbs; t += 256) {
    u32 flat = SI[t];
    if (flat / (u32)M == (u32)b) {
      u32 p = atomicAdd(&ovc, 1u);
      if (p < 256) { ovN[p] = (int)(flat % (u32)M); ovV[p] = SV[t]; }
    }
  }
  __syncthreads();
  const u32 no = ovc < 256u ? ovc : 256u;
  #pragma unroll
  for (int j = 0; j < 64; ++j) {
    const int col = tid * 64 + j;
    for (u32 i = 0; i < no; ++i) if (ovN[i] == col) v[j] = ovV[i];
  }
  #pragma unroll
  for (int j = 0; j < 16; ++j) {
    float4 t = make_float4(v[4 * j + 0], v[4 * j + 1], v[4 * j + 2], v[4 * j + 3]);
    reinterpret_cast<float4*>(rowp)[j] = t;
  }
  const int d0 = tid * 4;
  float4 acc = *reinterpret_cast<const float4*>(IB + d0);
  for (int cpart = 0; cpart < 8; ++cpart) {
    if (tid == 0) lc = 0;
    __syncthreads();
    if ((tid >> 5) == cpart) {
      #pragma unroll
      for (int j = 0; j < 64; ++j) {
        if (v[j] > 0.f) {
          u32 p = atomicAdd(&lc, 1u);
          lsN[p] = tid * 64 + j; lsV[p] = v[j];
        }
      }
    }
    __syncthreads();
    const u32 n = lc;
    for (u32 i = 0; i < n; ++i) {
      const float w = lsV[i];
      const float4 wv = *reinterpret_cast<const float4*>(WT + (size_t)lsN[i] * D + d0);
      acc.x = fmaf(w, wv.x, acc.x); acc.y = fmaf(w, wv.y, acc.y);
      acc.z = fmaf(w, wv.z, acc.z); acc.w = fmaf(w, wv.w, acc.w);
    }
    __syncthreads();
  }
  *reinterpret_cast<float4*>(RC + (size_t)b * D + d0) = acc;
}

extern "C" void kernel_launch(void* const* d_in, const int* in_sizes, int n_in,
                              void* d_out, int out_size, void* d_ws, size_t ws_size,
                              hipStream_t stream) {
  const float* x  = (const float*)d_in[0];
  const float* ew = (const float*)d_in[1];
  const float* dw = (const float*)d_in[2];
  const float* ib = (const float*)d_in[3];
  const float* nb = (const float*)d_in[4];
  const int* steps = (const int*)d_in[5];
  const int D = in_sizes[3];
  const int M = in_sizes[4];
  const int B = in_sizes[0] / D;
  const u32 K = (u32)(K_ACTIVE * B);

  float* out = (float*)d_out;
  float* recon  = out;
  float* activ  = out + (size_t)B * D;          // holds pre_act until final scatter
  float* mrecon = activ + (size_t)B * M;
  float* avals  = mrecon + (size_t)B * D;
  float* aidx   = avals + (size_t)B * AUX_K;

  // split-A operands live in output regions written LAST
  ushort_t* AH = (ushort_t*)recon;
  ushort_t* AL = (ushort_t*)mrecon;

  char* wsp = (char*)d_ws;
  size_t o = 0;
  auto alloc = [&](size_t bytes) { char* p = wsp + o; o += (bytes + 255) & ~(size_t)255; return p; };
  ushort_t* WH = (ushort_t*)alloc((size_t)M * D * 2);
  ushort_t* WL = (ushort_t*)alloc((size_t)M * D * 2);
  float* WT = (float*)alloc((size_t)M * D * 4);
  u32* H1   = (u32*)alloc(8192);
  u32* H2   = (u32*)alloc(8192);
  u32* PRM  = (u32*)alloc(256);
  u32* CF   = (u32*)alloc((size_t)M * 4);
  u32* CM   = (u32*)alloc((size_t)M * 4);
  u32* DW   = (u32*)alloc((size_t)(M / 32) * 4);
  float* BV = (float*)alloc((size_t)BUF_CAP * 4);
  u32* BI   = (u32*)alloc((size_t)BUF_CAP * 4);
  float* BV2 = (float*)alloc((size_t)SORT_CAP * 4);
  u32* BI2   = (u32*)alloc((size_t)SORT_CAP * 4);
  float* SV = (float*)alloc((size_t)SORT_CAP * 4);
  u32* SI   = (u32*)alloc((size_t)SORT_CAP * 4);
  (void)ws_size; (void)n_in; (void)out_size;

  hipMemsetAsync(H1, 0, 8192, stream);
  hipMemsetAsync(H2, 0, 8192, stream);
  hipMemsetAsync(PRM, 0, 256, stream);
  hipMemsetAsync(CF, 0, (size_t)M * 4, stream);
  hipMemsetAsync(CM, 0, (size_t)M * 4, stream);

  convA_k<<<(B * D / 8 + 255) / 256, 256, 0, stream>>>(x, ib, AH, AL, D);
  convW_k<<<((size_t)M * D / 8 + 255) / 256, 256, 0, stream>>>(ew, WH, WL);
  transpose_k<<<dim3(M / 32, D / 32), dim3(32, 8), 0, stream>>>(dw, WT, D, M);
  gemm_mfma<<<dim3(M / 128, B / 128), 256, 32768, stream>>>(AH, AL, WH, WL, nb, activ, H1, CM, M);

  const size_t N4 = (size_t)B * M / 4;
  const float4* act4 = (const float4*)activ;
  scan_k<<<1, 256, 0, stream>>>(H1, PRM, K, 1);
  hist2_k<<<2048, 256, 0, stream>>>(act4, N4, PRM, H2, BV, BI);
  scan_k<<<1, 256, 0, stream>>>(H2, PRM, K, 2);
  collect2_k<<<64, 256, 0, stream>>>(PRM, BV, BI, BV2, BI2);
  sortmark_k<<<1, 256, 0, stream>>>(PRM, BV2, BI2, SV, SI, CF, M);
  dead_k<<<(M / 32 + 255) / 256, 256, 0, stream>>>(CF, CM, steps, PRM, DW, M);
  rowk_multik<<<B, 256, 0, stream>>>(activ, WT, ib, mrecon, M, D);
  rowk_aux<<<B, 256, 0, stream>>>(activ, DW, avals, aidx, M);
  rowk_scatter<<<B, 256, 0, stream>>>(activ, WT, ib, recon, PRM, SV, SI, M, D);
}

// Round 18
// 1461.751 us; speedup vs baseline: 1.0185x; 1.0185x over previous
//
#include <hip/hip_runtime.h>

#define K_ACTIVE 32
#define MULTI_K 64
#define AUX_K 64
#define DEAD_THRESH 256
#define BUF_CAP 2097152u
#define STG_CAP 4096
#define SORT_CAP 4096

typedef unsigned int u32;
typedef unsigned long long u64;
typedef unsigned short ushort_t;
typedef __bf16 bf16x8 __attribute__((ext_vector_type(8)));
typedef float f32x4 __attribute__((ext_vector_type(4)));

__device__ __forceinline__ u32 fmap_signed_bits(u32 u) {
  return (u & 0x80000000u) ? ~u : (u | 0x80000000u);
}

__device__ __forceinline__ u32 bf16_rne(float f) {
  u32 u = __float_as_uint(f);
  return (u + 0x7FFFu + ((u >> 16) & 1u)) >> 16;
}

__device__ __forceinline__ void gload16(const void* g, void* s) {
  __builtin_amdgcn_global_load_lds(
      (const __attribute__((address_space(1))) void*)g,
      (__attribute__((address_space(3))) void*)s, 16, 0, 0);
}

// ---------------- transpose dec_w [D,M] -> dec_wT [M,D] ----------------
__global__ void transpose_k(const float* __restrict__ in, float* __restrict__ out, int D, int M) {
  __shared__ float tile[32][33];
  const int bx = blockIdx.x * 32;
  const int by = blockIdx.y * 32;
  const int tx = threadIdx.x, ty = threadIdx.y;
  #pragma unroll
  for (int i = 0; i < 32; i += 8)
    tile[ty + i][tx] = in[(size_t)(by + ty + i) * M + bx + tx];
  __syncthreads();
  #pragma unroll
  for (int i = 0; i < 32; i += 8)
    out[(size_t)(bx + ty + i) * D + by + tx] = tile[tx][ty + i];
}

// ---------------- split conversions ----------------
__global__ void convA_k(const float* __restrict__ X, const float* __restrict__ IB,
                        ushort_t* __restrict__ AH, ushort_t* __restrict__ AL, int D) {
  const int idx = blockIdx.x * 256 + threadIdx.x;
  const int row = idx >> 7;
  const int dpos = (idx & 127) << 3;
  const float4* xr = reinterpret_cast<const float4*>(X + (size_t)row * D + dpos);
  const float4* br = reinterpret_cast<const float4*>(IB + dpos);
  float4 x0 = xr[0], x1 = xr[1], b0 = br[0], b1 = br[1];
  float c[8] = {x0.x - b0.x, x0.y - b0.y, x0.z - b0.z, x0.w - b0.w,
                x1.x - b1.x, x1.y - b1.y, x1.z - b1.z, x1.w - b1.w};
  u32 hw[4], lw[4];
  #pragma unroll
  for (int j = 0; j < 4; ++j) {
    u32 h0 = bf16_rne(c[2 * j]), h1 = bf16_rne(c[2 * j + 1]);
    float r0 = c[2 * j] - __uint_as_float(h0 << 16);
    float r1 = c[2 * j + 1] - __uint_as_float(h1 << 16);
    hw[j] = h0 | (h1 << 16);
    lw[j] = bf16_rne(r0) | (bf16_rne(r1) << 16);
  }
  reinterpret_cast<uint4*>(AH)[idx] = make_uint4(hw[0], hw[1], hw[2], hw[3]);
  reinterpret_cast<uint4*>(AL)[idx] = make_uint4(lw[0], lw[1], lw[2], lw[3]);
}

__global__ void convW_k(const float* __restrict__ W,
                        ushort_t* __restrict__ WH, ushort_t* __restrict__ WL) {
  const int idx = blockIdx.x * 256 + threadIdx.x;
  const float4* wr = reinterpret_cast<const float4*>(W) + (size_t)idx * 2;
  float4 x0 = wr[0], x1 = wr[1];
  float c[8] = {x0.x, x0.y, x0.z, x0.w, x1.x, x1.y, x1.z, x1.w};
  u32 hw[4], lw[4];
  #pragma unroll
  for (int j = 0; j < 4; ++j) {
    u32 h0 = bf16_rne(c[2 * j]), h1 = bf16_rne(c[2 * j + 1]);
    float r0 = c[2 * j] - __uint_as_float(h0 << 16);
    float r1 = c[2 * j + 1] - __uint_as_float(h1 << 16);
    hw[j] = h0 | (h1 << 16);
    lw[j] = bf16_rne(r0) | (bf16_rne(r1) << 16);
  }
  reinterpret_cast<uint4*>(WH)[idx] = make_uint4(hw[0], hw[1], hw[2], hw[3]);
  reinterpret_cast<uint4*>(WL)[idx] = make_uint4(lw[0], lw[1], lw[2], lw[3]);
}

// ---------------- MFMA GEMM (+ fused hist1 + col-max in epilogue) ----------------
// r15/r16 lessons: pre_act sweeps are ~free (L3-resident) so no candidate
// capture; zero-skip halves the epilogue's same-address LDS atomics.
__global__ __launch_bounds__(256) void gemm_mfma(
    const ushort_t* __restrict__ AH, const ushort_t* __restrict__ AL,
    const ushort_t* __restrict__ WH, const ushort_t* __restrict__ WL,
    const float* __restrict__ NB, float* __restrict__ OUT,
    u32* __restrict__ GH, u32* __restrict__ CM, int M) {
  extern __shared__ char smem[];                 // 32768 B
  ushort_t* sA = (ushort_t*)smem;
  ushort_t* sB = (ushort_t*)(smem + 16384);
  const int tid = threadIdx.x;
  const int wave = tid >> 6, lane = tid & 63;
  const int bm = blockIdx.y * 128, bn = blockIdx.x * 128;
  const int wm = wave & 1, wn = wave >> 1;

  f32x4 acc[4][4];
  #pragma unroll
  for (int i = 0; i < 4; ++i)
    #pragma unroll
    for (int j = 0; j < 4; ++j) acc[i][j] = (f32x4){0.f, 0.f, 0.f, 0.f};

  int rowA[4], cbS[4];
  #pragma unroll
  for (int r = 0; r < 4; ++r) {
    int o = ((wave << 2) + r) * 1024 + lane * 16;
    int row = o >> 7;
    int cb = o & 127;
    rowA[r] = row;
    cbS[r] = cb ^ ((row & 7) << 4);   // pre-swizzled source column byte (rule #21)
  }
  const int cl = lane & 15, kg = lane >> 4;

  for (int kt = 0; kt < 48; ++kt) {
    const int ph = kt >> 4;
    const size_t kb = (size_t)((kt & 15) << 6) * 2;
    const ushort_t* Asrc = (ph == 1) ? AL : AH;
    const ushort_t* Bsrc = (ph == 2) ? WL : WH;
    #pragma unroll
    for (int r = 0; r < 4; ++r) {
      gload16((const char*)Asrc + ((size_t)(bm + rowA[r]) * 2048 + kb + cbS[r]),
              (char*)sA + (((wave << 2) + r) << 10));
      gload16((const char*)Bsrc + ((size_t)(bn + rowA[r]) * 2048 + kb + cbS[r]),
              (char*)sB + (((wave << 2) + r) << 10));
    }
    __syncthreads();
    #pragma unroll
    for (int ks = 0; ks < 2; ++ks) {
      const int kbyte = ks * 64 + kg * 16;
      bf16x8 af[4], bfr[4];
      #pragma unroll
      for (int mi = 0; mi < 4; ++mi) {
        const int rA = wm * 64 + mi * 16 + cl;
        af[mi] = *reinterpret_cast<const bf16x8*>(
            (const char*)sA + rA * 128 + (kbyte ^ ((rA & 7) << 4)));
      }
      #pragma unroll
      for (int ni = 0; ni < 4; ++ni) {
        const int rB = wn * 64 + ni * 16 + cl;
        bfr[ni] = *reinterpret_cast<const bf16x8*>(
            (const char*)sB + rB * 128 + (kbyte ^ ((rB & 7) << 4)));
      }
      #pragma unroll
      for (int mi = 0; mi < 4; ++mi)
        #pragma unroll
        for (int ni = 0; ni < 4; ++ni)
          acc[mi][ni] = __builtin_amdgcn_mfma_f32_16x16x32_bf16(af[mi], bfr[ni], acc[mi][ni], 0, 0, 0);
    }
    __syncthreads();
  }

  // epilogue: 4-replica 2048-bin histogram (hist1, zero-skipped) + col-max (CM)
  u32* eh = (u32*)smem;
  for (int i = tid; i < 8192; i += 256) eh[i] = 0;
  __syncthreads();
  const int rg = lane >> 4;
  const int rb = (lane & 3) * 2048;
  u32 zcnt = 0;
  #pragma unroll
  for (int ni = 0; ni < 4; ++ni) {
    const int col = bn + wn * 64 + ni * 16 + cl;
    const float nbv = NB[col];
    float mx = 0.f;
    #pragma unroll
    for (int mi = 0; mi < 4; ++mi) {
      const int row0 = bm + wm * 64 + mi * 16 + rg * 4;
      #pragma unroll
      for (int r = 0; r < 4; ++r) {
        const float val = acc[mi][ni][r] + nbv;
        OUT[(size_t)(row0 + r) * M + col] = val;
        const float a = (val > 0.f) ? val : 0.f;
        mx = fmaxf(mx, a);
        const u32 bin = __float_as_uint(a) >> 21;
        if (bin) atomicAdd(&eh[rb + bin], 1u); else ++zcnt;  // zero-skip (~50%)
      }
    }
    mx = fmaxf(mx, __shfl_xor(mx, 16));
    mx = fmaxf(mx, __shfl_xor(mx, 32));
    if (rg == 0) atomicMax(&CM[col], __float_as_uint(mx));
  }
  #pragma unroll
  for (int o = 32; o > 0; o >>= 1) zcnt += __shfl_down(zcnt, o);
  if (lane == 0 && zcnt) atomicAdd(&eh[0], zcnt);
  __syncthreads();
  for (int i = tid; i < 2048; i += 256) {
    u32 s = eh[i] + eh[2048 + i] + eh[4096 + i] + eh[6144 + i];
    if (s) atomicAdd(&GH[i], s);
  }
}

// parallel suffix-scan cutoff finder; phase 1: bits[31:21]; phase 2: bits[20:10]
__global__ void scan_k(const u32* __restrict__ H, u32* __restrict__ PRM, u32 K, int phase) {
  __shared__ u32 suf[256];
  const int t = threadIdx.x;
  u32 h[8], ls[8];
  #pragma unroll
  for (int j = 0; j < 8; ++j) h[j] = H[t * 8 + j];
  u32 run = 0;
  #pragma unroll
  for (int j = 7; j >= 0; --j) { run += h[j]; ls[j] = run; }
  suf[t] = run;
  __syncthreads();
  for (int off = 1; off < 256; off <<= 1) {
    u32 v = (t + off < 256) ? suf[t + off] : 0u;
    __syncthreads();
    suf[t] += v;
    __syncthreads();
  }
  const u32 rightOf = (t < 255) ? suf[t + 1] : 0u;
  const u32 base = (phase == 2) ? PRM[1] : 0u;
  #pragma unroll
  for (int j = 0; j < 8; ++j) {
    u32 Sb = base + rightOf + ls[j];
    u32 Sb1 = base + rightOf + ((j < 7) ? ls[j + 1] : 0u);
    if (Sb >= K && Sb1 < K) {
      int b = t * 8 + j;
      if (phase == 1) { PRM[0] = (u32)b; PRM[1] = Sb1; }
      else { PRM[2] = (PRM[0] << 11) | (u32)b; PRM[3] = K - Sb1; }
    }
  }
}

// hist2: refine bin1 by next 11 bits; stage bin1 candidates per-block in LDS
__global__ void hist2_k(const float4* __restrict__ P4, size_t N4, u32* __restrict__ PRM,
                        u32* __restrict__ GH, float* __restrict__ BV, u32* __restrict__ BI) {
  __shared__ float sv[STG_CAP];
  __shared__ u32 si[STG_CAP];
  __shared__ u32 scnt, sbase;
  const int tid = threadIdx.x;
  if (tid == 0) scnt = 0;
  __syncthreads();
  const u32 b1 = PRM[0];
  const size_t step = (size_t)gridDim.x * blockDim.x;
  for (size_t i = (size_t)blockIdx.x * blockDim.x + tid; i < N4; i += step) {
    float4 vv = P4[i];
    float va[4] = {vv.x, vv.y, vv.z, vv.w};
    #pragma unroll
    for (int c = 0; c < 4; ++c) {
      float a = (va[c] > 0.f) ? va[c] : 0.f;
      u32 u = __float_as_uint(a);
      if ((u >> 21) == b1) {
        atomicAdd(&GH[(u >> 10) & 2047u], 1u);
        u32 p = atomicAdd(&scnt, 1u);
        if (p < STG_CAP) { sv[p] = a; si[p] = (u32)(i * 4 + c); }
        else {
          u32 g = atomicAdd(&PRM[8], 1u);
          if (g < BUF_CAP) { BV[g] = a; BI[g] = (u32)(i * 4 + c); }
        }
      }
    }
  }
  __syncthreads();
  u32 n = scnt < STG_CAP ? scnt : STG_CAP;
  if (tid == 0) sbase = atomicAdd(&PRM[8], n);
  __syncthreads();
  const u32 base = sbase;
  for (u32 i = tid; i < n; i += 256) {
    u32 g = base + i;
    if (g < BUF_CAP) { BV[g] = sv[i]; BI[g] = si[i]; }
  }
}

// collect2: filter stored bin1 candidates down to the 22-bit cutoff bin (tiny pass)
__global__ void collect2_k(u32* __restrict__ PRM, const float* __restrict__ BV,
                           const u32* __restrict__ BI, float* __restrict__ BV2,
                           u32* __restrict__ BI2) {
  const u32 pc = PRM[2];
  u32 nb1 = PRM[8]; if (nb1 > BUF_CAP) nb1 = BUF_CAP;
  const u32 step = gridDim.x * blockDim.x;
  for (u32 i = blockIdx.x * blockDim.x + threadIdx.x; i < nb1; i += step) {
    float a = BV[i];
    if ((__float_as_uint(a) >> 10) == pc) {
      u32 pos = atomicAdd(&PRM[9], 1u);
      if (pos < SORT_CAP) { BV2[pos] = a; BI2[pos] = BI[i]; }
    }
  }
}

__global__ void sortmark_k(u32* __restrict__ PRM, const float* __restrict__ BV, const u32* __restrict__ BI,
                           float* __restrict__ SV, u32* __restrict__ SI, u32* __restrict__ CF, int M) {
  __shared__ u64 keys[SORT_CAP];
  const int tid = threadIdx.x;
  u32 nb = PRM[9]; if (nb > SORT_CAP) nb = SORT_CAP;
  const u32 krem = PRM[3];
  if (nb == 0) { if (tid == 0) PRM[5] = 0; return; }
  u32 np = 1; while (np < nb) np <<= 1;
  for (u32 i = tid; i < np; i += 256)
    keys[i] = (i < nb) ? ((((u64)__float_as_uint(BV[i])) << 32) | (u64)(0xFFFFFFFFu - BI[i])) : 0ull;
  __syncthreads();
  for (u32 k = 2; k <= np; k <<= 1) {
    for (u32 j = k >> 1; j > 0; j >>= 1) {
      for (u32 i = tid; i < np; i += 256) {
        u32 ixj = i ^ j;
        if (ixj > i) {
          u64 a = keys[i], b = keys[ixj];
          bool up = ((i & k) == 0);
          if (up ? (a < b) : (a > b)) { keys[i] = b; keys[ixj] = a; }
        }
      }
      __syncthreads();
    }
  }
  u32 nsel = krem < nb ? krem : nb;
  for (u32 t = tid; t < nsel; t += 256) {
    u64 kk = keys[t];
    u32 flat = 0xFFFFFFFFu - (u32)(kk & 0xFFFFFFFFull);
    float val = __uint_as_float((u32)(kk >> 32));
    SI[t] = flat; SV[t] = val;
    if (val > 0.f) CF[flat % (u32)M] = 1u;
  }
  if (tid == 0) PRM[5] = nsel;
}

// ---------------- dead mask: active = boundary-mark OR col-max above cutoff bin ----------------
__global__ void dead_k(const u32* __restrict__ CF, const u32* __restrict__ CM,
                       const int* __restrict__ ST, const u32* __restrict__ PRM,
                       u32* __restrict__ DW, int M) {
  int w = blockIdx.x * blockDim.x + threadIdx.x;
  if (w >= M / 32) return;
  const u32 pc = PRM[2];
  u32 bits = 0;
  for (int i = 0; i < 32; ++i) {
    int n = w * 32 + i;
    bool active = (CF[n] != 0) || ((CM[n] >> 10) > pc);
    if (!active && (ST[n] + 1) > DEAD_THRESH) bits |= (1u << i);
  }
  DW[w] = bits;
}

// ---------------- per-row top-64 select (value desc, index asc) ----------------
struct TopkSh {
  u32 hist[16 * 257];
  u32 wred[4];
  u32 prefix, need, scnt;
  int selN[64];
  float selV[64];
};

template<bool ZSKIP>
__device__ __forceinline__ void row_topk64(const float (&v)[64], int tid, TopkSh* S) {
  const int lane = tid & 63, wid = tid >> 6;
  u32 zp = 0, zn = 0;
  if (ZSKIP) {
    #pragma unroll
    for (int j = 0; j < 64; ++j) {
      u32 ub = __float_as_uint(v[j]);
      zp += (ub == 0u);
      zn += (ub == 0x80000000u);
    }
    #pragma unroll
    for (int o = 32; o > 0; o >>= 1) { zp += __shfl_down(zp, o); zn += __shfl_down(zn, o); }
  }
  u32 pref = 0, need = 64;
  for (int p = 0; p < 4; ++p) {
    const int sh = 24 - 8 * p;
    for (int i = tid; i < 16 * 257; i += 256) S->hist[i] = 0;
    if (p == 0 && tid == 0) S->scnt = 0;
    __syncthreads();
    const int rb = (tid & 15) * 257;
    #pragma unroll
    for (int j = 0; j < 64; ++j) {
      u32 ub = __float_as_uint(v[j]);
      if (ZSKIP && ((ub << 1) == 0u)) continue;
      u32 mu = fmap_signed_bits(ub);
      if (p == 0 || (mu >> (sh + 8)) == pref)
        atomicAdd(&S->hist[rb + ((mu >> sh) & 255u)], 1u);
    }
    if (ZSKIP && lane == 0) {
      const u32 mup = 0x80000000u, mun = 0x7FFFFFFFu;
      if (zp && (p == 0 || (mup >> (sh + 8)) == pref))
        atomicAdd(&S->hist[wid * 257 + ((mup >> sh) & 255u)], zp);
      if (zn && (p == 0 || (mun >> (sh + 8)) == pref))
        atomicAdd(&S->hist[wid * 257 + ((mun >> sh) & 255u)], zn);
    }
    __syncthreads();
    u32 own = 0;
    #pragma unroll
    for (int r = 0; r < 16; ++r) own += S->hist[r * 257 + tid];
    u32 x = own;
    #pragma unroll
    for (int o = 1; o < 64; o <<= 1) {
      u32 y = __shfl_down(x, o);
      x += (lane + o < 64) ? y : 0u;
    }
    if (lane == 0) S->wred[wid] = x;
    __syncthreads();
    u32 Sb = x;
    for (int w = wid + 1; w < 4; ++w) Sb += S->wred[w];
    u32 below = Sb - own;
    if (Sb >= need && below < need) {
      S->prefix = (pref << 8) | (u32)tid;
      S->need = need - below;
    }
    __syncthreads();
    pref = S->prefix; need = S->need;
  }
  const u32 muc = pref, neq = need;
  u32 myeq = 0;
  #pragma unroll
  for (int j = 0; j < 64; ++j) {
    u32 mu = fmap_signed_bits(__float_as_uint(v[j]));
    if (mu > muc) {
      u32 pos = atomicAdd(&S->scnt, 1u);
      S->selN[pos] = tid * 64 + j;
      S->selV[pos] = v[j];
    } else if (mu == muc) ++myeq;
  }
  u32 xs = myeq;
  #pragma unroll
  for (int o = 1; o < 64; o <<= 1) {
    u32 y = __shfl_up(xs, o);
    xs += (lane >= o) ? y : 0u;
  }
  if (lane == 63) S->wred[wid] = xs;
  __syncthreads();
  u32 base = 0;
  for (int w = 0; w < wid; ++w) base += S->wred[w];
  u32 g = base + xs - myeq;
  const u32 a0 = S->scnt;
  #pragma unroll
  for (int j = 0; j < 64; ++j) {
    u32 mu = fmap_signed_bits(__float_as_uint(v[j]));
    if (mu == muc) {
      if (g < neq) { S->selN[a0 + g] = tid * 64 + j; S->selV[a0 + g] = v[j]; }
      ++g;
    }
  }
  __syncthreads();
}

__device__ __forceinline__ void load_row64(const float* rowp, float (&v)[64]) {
  #pragma unroll
  for (int j = 0; j < 16; ++j) {
    float4 t = reinterpret_cast<const float4*>(rowp)[j];
    v[4 * j + 0] = t.x; v[4 * j + 1] = t.y; v[4 * j + 2] = t.z; v[4 * j + 3] = t.w;
  }
}

// ---------------- multik top-64 + decode ----------------
__launch_bounds__(256, 2)
__global__ void rowk_multik(const float* __restrict__ PRE, const float* __restrict__ WT,
                            const float* __restrict__ IB, float* __restrict__ MR,
                            int M, int D) {
  __shared__ TopkSh S;
  const int b = blockIdx.x, tid = threadIdx.x;
  float v[64];
  load_row64(PRE + (size_t)b * M + tid * 64, v);
  row_topk64<false>(v, tid, &S);
  const int d0 = tid * 4;
  float4 acc = *reinterpret_cast<const float4*>(IB + d0);
  for (int i = 0; i < 64; ++i) {
    float w = S.selV[i];
    if (w > 0.f) {
      const float4 wv = *reinterpret_cast<const float4*>(WT + (size_t)S.selN[i] * D + d0);
      acc.x = fmaf(w, wv.x, acc.x); acc.y = fmaf(w, wv.y, acc.y);
      acc.z = fmaf(w, wv.z, acc.z); acc.w = fmaf(w, wv.w, acc.w);
    }
  }
  *reinterpret_cast<float4*>(MR + (size_t)b * D + d0) = acc;
}

// ---------------- aux top-64 over dead_pre with exact tie semantics ----------------
__launch_bounds__(256, 2)
__global__ void rowk_aux(const float* __restrict__ PRE, const u32* __restrict__ DW,
                         float* __restrict__ AV, float* __restrict__ AI, int M) {
  __shared__ TopkSh S;
  __shared__ u64 skey[64];
  __shared__ int sN2[64];
  __shared__ float sV2[64];
  const int b = blockIdx.x, tid = threadIdx.x;
  float v[64];
  load_row64(PRE + (size_t)b * M + tid * 64, v);
  const u32 mw0 = DW[tid * 2], mw1 = DW[tid * 2 + 1];
  #pragma unroll
  for (int j = 0; j < 64; ++j) {
    u32 bit = ((j < 32 ? mw0 : mw1) >> (j & 31)) & 1u;
    v[j] = bit ? v[j] : (v[j] * 0.0f);   // preserves signed zero like the reference
  }
  row_topk64<true>(v, tid, &S);
  if (tid < 64) {
    float vv = S.selV[tid];
    int col = S.selN[tid];
    u32 mu = fmap_signed_bits(__float_as_uint(vv));
    skey[tid] = (((u64)mu) << 32) | (u64)(0xFFFFFFFFu - (u32)col);
  }
  __syncthreads();
  if (tid < 64) {
    u64 mine = skey[tid];
    int rank = 0;
    for (int j = 0; j < 64; ++j) rank += (skey[j] > mine) ? 1 : 0;
    sN2[rank] = S.selN[tid]; sV2[rank] = S.selV[tid];
  }
  __syncthreads();
  if (tid < 64) {
    AV[(size_t)b * AUX_K + tid] = sV2[tid] > 0.f ? sV2[tid] : 0.f;
    AI[(size_t)b * AUX_K + tid] = (float)sN2[tid];
  }
}

// ---------------- activ scatter (in place) + sparse recon decode ----------------
__launch_bounds__(256, 2)
__global__ void rowk_scatter(float* __restrict__ ACT, const float* __restrict__ WT,
                             const float* __restrict__ IB, float* __restrict__ RC,
                             const u32* __restrict__ PRM, const float* __restrict__ SV,
                             const u32* __restrict__ SI, int M, int D) {
  __shared__ int lsN[2048]; __shared__ float lsV[2048];
  __shared__ int ovN[256]; __shared__ float ovV[256];
  __shared__ u32 ovc, lc;
  const int b = blockIdx.x, tid = threadIdx.x;
  float* rowp = ACT + (size_t)b * M + tid * 64;
  float v[64];
  load_row64(rowp, v);
  const u32 pc = PRM[2];
  #pragma unroll
  for (int j = 0; j < 64; ++j) {
    float a = (v[j] > 0.f) ? v[j] : 0.f;
    v[j] = ((__float_as_uint(a) >> 10) > pc) ? a : 0.f;
  }
  if (tid == 0) ovc = 0;
  __syncthreads();
  const u32 nbs = PRM[5];
  for (u32 t = tid; t < nbs; t += 256) {
    u32 flat = SI[t];
    if (flat / (u32)M == (u32)b) {
      u32 p = atomicAdd(&ovc, 1u);
      if (p < 256) { ovN[p] = (int)(flat % (u32)M); ovV[p] = SV[t]; }
    }
  }
  __syncthreads();
  const u32 no = ovc < 256u ? ovc : 256u;
  #pragma unroll
  for (int j = 0; j < 64; ++j) {
    const int col = tid * 64 + j;
    for (u32 i = 0; i < no; ++i) if (ovN[i] == col) v[j] = ovV[i];
  }
  #pragma unroll
  for (int j = 0; j < 16; ++j) {
    float4 t = make_float4(v[4 * j + 0], v[4 * j + 1], v[4 * j + 2], v[4 * j + 3]);
    reinterpret_cast<float4*>(rowp)[j] = t;
  }
  const int d0 = tid * 4;
  float4 acc = *reinterpret_cast<const float4*>(IB + d0);
  for (int cpart = 0; cpart < 8; ++cpart) {
    if (tid == 0) lc = 0;
    __syncthreads();
    if ((tid >> 5) == cpart) {
      #pragma unroll
      for (int j = 0; j < 64; ++j) {
        if (v[j] > 0.f) {
          u32 p = atomicAdd(&lc, 1u);
          lsN[p] = tid * 64 + j; lsV[p] = v[j];
        }
      }
    }
    __syncthreads();
    const u32 n = lc;
    for (u32 i = 0; i < n; ++i) {
      const float w = lsV[i];
      const float4 wv = *reinterpret_cast<const float4*>(WT + (size_t)lsN[i] * D + d0);
      acc.x = fmaf(w, wv.x, acc.x); acc.y = fmaf(w, wv.y, acc.y);
      acc.z = fmaf(w, wv.z, acc.z); acc.w = fmaf(w, wv.w, acc.w);
    }
    __syncthreads();
  }
  *reinterpret_cast<float4*>(RC + (size_t)b * D + d0) = acc;
}

extern "C" void kernel_launch(void* const* d_in, const int* in_sizes, int n_in,
                              void* d_out, int out_size, void* d_ws, size_t ws_size,
                              hipStream_t stream) {
  const float* x  = (const float*)d_in[0];
  const float* ew = (const float*)d_in[1];
  const float* dw = (const float*)d_in[2];
  const float* ib = (const float*)d_in[3];
  const float* nb = (const float*)d_in[4];
  const int* steps = (const int*)d_in[5];
  const int D = in_sizes[3];
  const int M = in_sizes[4];
  const int B = in_sizes[0] / D;
  const u32 K = (u32)(K_ACTIVE * B);

  float* out = (float*)d_out;
  float* recon  = out;
  float* activ  = out + (size_t)B * D;          // holds pre_act until final scatter
  float* mrecon = activ + (size_t)B * M;
  float* avals  = mrecon + (size_t)B * D;
  float* aidx   = avals + (size_t)B * AUX_K;

  // split-A operands live in output regions written LAST
  ushort_t* AH = (ushort_t*)recon;
  ushort_t* AL = (ushort_t*)mrecon;

  char* wsp = (char*)d_ws;
  size_t o = 0;
  auto alloc = [&](size_t bytes) { char* p = wsp + o; o += (bytes + 255) & ~(size_t)255; return p; };
  ushort_t* WH = (ushort_t*)alloc((size_t)M * D * 2);
  ushort_t* WL = (ushort_t*)alloc((size_t)M * D * 2);
  float* WT = (float*)alloc((size_t)M * D * 4);
  u32* H1   = (u32*)alloc(8192);
  u32* H2   = (u32*)alloc(8192);
  u32* PRM  = (u32*)alloc(256);
  u32* CF   = (u32*)alloc((size_t)M * 4);
  u32* CM   = (u32*)alloc((size_t)M * 4);
  u32* DW   = (u32*)alloc((size_t)(M / 32) * 4);
  float* BV = (float*)alloc((size_t)BUF_CAP * 4);
  u32* BI   = (u32*)alloc((size_t)BUF_CAP * 4);
  float* BV2 = (float*)alloc((size_t)SORT_CAP * 4);
  u32* BI2   = (u32*)alloc((size_t)SORT_CAP * 4);
  float* SV = (float*)alloc((size_t)SORT_CAP * 4);
  u32* SI   = (u32*)alloc((size_t)SORT_CAP * 4);
  (void)ws_size; (void)n_in; (void)out_size;

  hipMemsetAsync(H1, 0, 8192, stream);
  hipMemsetAsync(H2, 0, 8192, stream);
  hipMemsetAsync(PRM, 0, 256, stream);
  hipMemsetAsync(CF, 0, (size_t)M * 4, stream);
  hipMemsetAsync(CM, 0, (size_t)M * 4, stream);

  convA_k<<<(B * D / 8 + 255) / 256, 256, 0, stream>>>(x, ib, AH, AL, D);
  convW_k<<<((size_t)M * D / 8 + 255) / 256, 256, 0, stream>>>(ew, WH, WL);
  transpose_k<<<dim3(M / 32, D / 32), dim3(32, 8), 0, stream>>>(dw, WT, D, M);
  gemm_mfma<<<dim3(M / 128, B / 128), 256, 32768, stream>>>(AH, AL, WH, WL, nb, activ, H1, CM, M);

  const size_t N4 = (size_t)B * M / 4;
  const float4* act4 = (const float4*)activ;
  scan_k<<<1, 256, 0, stream>>>(H1, PRM, K, 1);
  hist2_k<<<2048, 256, 0, stream>>>(act4, N4, PRM, H2, BV, BI);
  scan_k<<<1, 256, 0, stream>>>(H2, PRM, K, 2);
  collect2_k<<<64, 256, 0, stream>>>(PRM, BV, BI, BV2, BI2);
  sortmark_k<<<1, 256, 0, stream>>>(PRM, BV2, BI2, SV, SI, CF, M);
  dead_k<<<(M / 32 + 255) / 256, 256, 0, stream>>>(CF, CM, steps, PRM, DW, M);
  rowk_multik<<<B, 256, 0, stream>>>(activ, WT, ib, mrecon, M, D);
  rowk_aux<<<B, 256, 0, stream>>>(activ, DW, avals, aidx, M);
  rowk_scatter<<<B, 256, 0, stream>>>(activ, WT, ib, recon, PRM, SV, SI, M, D);
}